// Round 3
// baseline (680.452 us; speedup 1.0000x reference)
//
#include <hip/hip_runtime.h>

#define BB 4096
#define NN 32768
#define LL 12
#define KK 64
#define SLOTS (LL * KK)   // 768

// ---------------------------------------------------------------------------
// R2 post-mortem: random per-lane gather is stuck at ~1 TB/s (DRAM
// activation-bound scattered 128B lines; MLP was already saturating in both
// R1 and R2 -> identical times). Fix: stream x sequentially (6.3 TB/s),
// extract the needed 768 columns per row through LDS, then run the softmax
// from a compact G[B][768] with fully coalesced reads.
// ---------------------------------------------------------------------------

// K_A: one block per row b. Stage the full 128 KB row in LDS (coalesced
// float4 stream), then threads 0..767 extract row[brother[t]] -> G[b][t].
__global__ __launch_bounds__(1024) void extract_rows(
    const float* __restrict__ x,
    const int* __restrict__ brother,
    float* __restrict__ G) {
    __shared__ float row[NN];                       // 128 KB (<160 KB/CU)
    const int b = blockIdx.x;
    const float4* __restrict__ src = (const float4*)(x + (size_t)b * NN);
    float4* dst = (float4*)row;
    #pragma unroll
    for (int i = 0; i < NN / 4 / 1024; ++i)         // 8 float4 per thread
        dst[threadIdx.x + i * 1024] = src[threadIdx.x + i * 1024];
    __syncthreads();
    if (threadIdx.x < SLOTS)
        G[(size_t)b * SLOTS + threadIdx.x] = row[brother[threadIdx.x]];
}

// K_B: wave per (l, chunk of 8 rows); reads from G are contiguous 256 B.
constexpr int CHUNK = 8;
constexpr int NWAVES = LL * (BB / CHUNK);           // 6144
constexpr int WPB = 4;
constexpr int NBLOCKS = NWAVES / WPB;               // 1536

__global__ __launch_bounds__(256) void hsm_partial(
    const float* __restrict__ G,
    const int* __restrict__ brother,
    const int* __restrict__ p_y,
    float* __restrict__ partials) {

    const int wave_in_block = threadIdx.x >> 6;
    const int lane = threadIdx.x & 63;
    const int wid = blockIdx.x * WPB + wave_in_block;
    const int chunk = wid / LL;
    const int l = wid - chunk * LL;
    const int b0 = chunk * CHUNK;

    const int col = brother[l * KK + lane];
    const int label = __ffsll(__ballot(col == p_y[l])) - 1;

    const float* __restrict__ gp = G + (size_t)b0 * SLOTS + l * KK + lane;

    float v[CHUNK];
    #pragma unroll
    for (int bi = 0; bi < CHUNK; ++bi)
        v[bi] = gp[(size_t)bi * SLOTS];

    float local = 0.f;
    #pragma unroll
    for (int bi = 0; bi < CHUNK; ++bi) {
        float mx = v[bi];
        #pragma unroll
        for (int o = 32; o > 0; o >>= 1) mx = fmaxf(mx, __shfl_xor(mx, o));
        float s = __expf(v[bi] - mx);
        #pragma unroll
        for (int o = 32; o > 0; o >>= 1) s += __shfl_xor(s, o);
        local += mx + __logf(s) - __shfl(v[bi], label);
    }

    __shared__ float red[WPB];
    if (lane == 0) red[wave_in_block] = local;
    __syncthreads();
    if (threadIdx.x == 0) {
        float s = 0.f;
        #pragma unroll
        for (int i = 0; i < WPB; ++i) s += red[i];
        partials[blockIdx.x] = s;
    }
}

__global__ __launch_bounds__(256) void hsm_final(
    const float* __restrict__ partials, float* __restrict__ out, int n) {
    float s = 0.f;
    for (int i = threadIdx.x; i < n; i += 256) s += partials[i];
    #pragma unroll
    for (int o = 32; o > 0; o >>= 1) s += __shfl_xor(s, o);
    __shared__ float red[4];
    const int wave = threadIdx.x >> 6, lane = threadIdx.x & 63;
    if (lane == 0) red[wave] = s;
    __syncthreads();
    if (threadIdx.x == 0) {
        out[0] = (red[0] + red[1] + red[2] + red[3]) / (float)BB;
    }
}

extern "C" void kernel_launch(void* const* d_in, const int* in_sizes, int n_in,
                              void* d_out, int out_size, void* d_ws, size_t ws_size,
                              hipStream_t stream) {
    const float* x       = (const float*)d_in[0];
    const int*   brother = (const int*)d_in[1];
    const int*   p_y     = (const int*)d_in[2];
    // d_in[3] = y : unused by the reference
    float* out = (float*)d_out;

    float* G        = (float*)d_ws;                       // 4096*768 floats = 12.6 MB
    float* partials = G + (size_t)BB * SLOTS;             // + 6 KB

    extract_rows<<<BB, 1024, 0, stream>>>(x, brother, G);
    hsm_partial<<<NBLOCKS, 256, 0, stream>>>(G, brother, p_y, partials);
    hsm_final<<<1, 256, 0, stream>>>(partials, out, NBLOCKS);
}

// Round 5
// 645.664 us; speedup vs baseline: 1.0539x; 1.0539x over previous
//
#include <hip/hip_runtime.h>

#define BB 4096
#define NN 32768
#define LL 12
#define KK 64

// ---------------------------------------------------------------------------
// Model after R3: dur_us = ~565 us fixed harness reset traffic + T_kernel.
// R2's gather T ~= 71 us fetching 744 lines/row (12 l's in different blocks,
// no cross-l L2 dedupe). This version: one wave owns CHUNK=4 rows and ALL 12
// l's -> the 768 column-gathers per row issue from one CU back-to-back, so
// duplicate 128B lines across l's dedupe in that XCD's L2: 540 lines/row
// (283 MB) instead of 744 (390 MB), a 27% traffic cut.
// ---------------------------------------------------------------------------
constexpr int CHUNK = 4;                 // rows per wave
constexpr int NWAVES = BB / CHUNK;       // 1024 waves
constexpr int WPB = 4;                   // waves per block
constexpr int NBLOCKS = NWAVES / WPB;    // 256 blocks (1/CU)

__global__ __launch_bounds__(64) void zero_out(float* out, int n) {
    if ((int)threadIdx.x < n) out[threadIdx.x] = 0.f;
}

__global__ __launch_bounds__(256) void hsm_fused(
    const float* __restrict__ x,
    const int* __restrict__ brother,
    const int* __restrict__ p_y,
    float* __restrict__ out) {

    const int wave_in_block = threadIdx.x >> 6;
    const int lane = threadIdx.x & 63;
    const int wid = blockIdx.x * WPB + wave_in_block;
    const int b0 = wid * CHUNK;

    // per-l state: column for this lane, and the label lane (ballot)
    int col[LL];
    int label[LL];
    #pragma unroll
    for (int l = 0; l < LL; ++l) {
        col[l] = brother[l * KK + lane];
        label[l] = __ffsll(__ballot(col[l] == p_y[l])) - 1;
    }

    // issue all CHUNK*12 gathers (independent; same-row l's adjacent in
    // program order -> L1/L2 sector dedupe on this CU)
    float v[LL][CHUNK];
    #pragma unroll
    for (int c = 0; c < CHUNK; ++c) {
        const float* __restrict__ xr = x + (size_t)(b0 + c) * NN;
        #pragma unroll
        for (int l = 0; l < LL; ++l)
            v[l][c] = xr[col[l]];
    }

    // 48 independent logsumexp reductions (shuffle latency hidden by ILP)
    float local = 0.f;
    #pragma unroll
    for (int l = 0; l < LL; ++l) {
        #pragma unroll
        for (int c = 0; c < CHUNK; ++c) {
            const float val = v[l][c];
            float mx = val;
            #pragma unroll
            for (int o = 32; o > 0; o >>= 1) mx = fmaxf(mx, __shfl_xor(mx, o));
            float s = __expf(val - mx);
            #pragma unroll
            for (int o = 32; o > 0; o >>= 1) s += __shfl_xor(s, o);
            local += mx + __logf(s) - __shfl(val, label[l]);
        }
    }

    __shared__ float red[WPB];
    if (lane == 0) red[wave_in_block] = local;
    __syncthreads();
    if (threadIdx.x == 0) {
        float s = 0.f;
        #pragma unroll
        for (int i = 0; i < WPB; ++i) s += red[i];
        atomicAdd(out, s * (1.0f / (float)BB));   // 256 atomics total
    }
}

extern "C" void kernel_launch(void* const* d_in, const int* in_sizes, int n_in,
                              void* d_out, int out_size, void* d_ws, size_t ws_size,
                              hipStream_t stream) {
    const float* x       = (const float*)d_in[0];
    const int*   brother = (const int*)d_in[1];
    const int*   p_y     = (const int*)d_in[2];
    // d_in[3] = y : unused by the reference
    float* out = (float*)d_out;

    zero_out<<<1, 64, 0, stream>>>(out, out_size);   // d_out is 0xAA-poisoned
    hsm_fused<<<NBLOCKS, 256, 0, stream>>>(x, brother, p_y, out);
}